// Round 1
// baseline (46.755 us; speedup 1.0000x reference)
//
#include <hip/hip_runtime.h>
#include <math.h>

#define BTOT 262144
#define R 3
#define F 4
#define H 16
#define A 18
#define SMALL_NUM_F 0.015f

__global__ __launch_bounds__(256) void ftc_kernel(
    const float* __restrict__ s,
    const float* __restrict__ W1,
    const float* __restrict__ b1,
    const float* __restrict__ W2,
    const float* __restrict__ b2,
    const float* __restrict__ W3,
    const float* __restrict__ b3,
    const float* __restrict__ p_select,
    const float* __restrict__ leaves,
    const float* __restrict__ gumbel,
    float* __restrict__ out)
{
    __shared__ float sh_g[R][F];
    __shared__ float sh_cond[R];
    __shared__ float sh_leaves[4][A];
    __shared__ unsigned char sh_idx[256];

    const int tid = threadIdx.x;

    // --- per-(r,f) gumbel-softmax hard selection (uniform across batch) ---
    if (tid < R * F) {
        const int rf = tid;
        float l0 = p_select[rf * 2 + 0] + gumbel[rf * 2 + 0];
        float l1 = p_select[rf * 2 + 1] + gumbel[rf * 2 + 1];
        float mx = fmaxf(l0, l1);
        float e0 = expf(l0 - mx), e1 = expf(l1 - mx);
        float den = e0 + e1;
        float y0 = e0 / den, y1 = e1 / den;
        float ym = fmaxf(y0, y1);
        sh_g[rf / F][rf % F] = (y1 == ym) ? 1.0f : 0.0f;
    }
    // --- leaves softmax rows (4 x 18) ---
    if (tid < 4) {
        float mx = leaves[tid * A];
        for (int a = 1; a < A; ++a) mx = fmaxf(mx, leaves[tid * A + a]);
        float e[A];
        float sum = 0.f;
        for (int a = 0; a < A; ++a) { e[a] = expf(leaves[tid * A + a] - mx); sum += e[a]; }
        for (int a = 0; a < A; ++a) sh_leaves[tid][a] = e[a] / sum;
    }
    __syncthreads();
    if (tid < R) {
        float ssum = sh_g[tid][0] + sh_g[tid][1] + sh_g[tid][2] + sh_g[tid][3];
        sh_cond[tid] = (ssum > SMALL_NUM_F) ? 1.0f : 0.0f;
    }
    __syncthreads();

    const int b = blockIdx.x * 256 + tid;
    const float4 sv = *reinterpret_cast<const float4*>(s + (size_t)b * F);
    const float sf[F] = {sv.x, sv.y, sv.z, sv.w};

    float strength[R];
#pragma unroll
    for (int r = 0; r < R; ++r) {
        float m[F];
#pragma unroll
        for (int f = 0; f < F; ++f) {
            const int rf = r * F + f;
            const float* w1  = W1 + rf * H;
            const float* bb1 = b1 + rf * H;
            const float* w2  = W2 + rf * H * H;
            const float* bb2 = b2 + rf * H;
            const float* w3  = W3 + rf * H;

            float h1[H];
#pragma unroll
            for (int h = 0; h < H; ++h) {
                float v = fmaf(sf[f], w1[h], bb1[h]);
                h1[h] = fmaxf(v, 0.01f * v);   // lrelu, exact
            }
            float acc[H];
#pragma unroll
            for (int o = 0; o < H; ++o) acc[o] = bb2[o];
#pragma unroll
            for (int h = 0; h < H; ++h) {
                const float hv = h1[h];
#pragma unroll
                for (int o = 0; o < H; ++o)
                    acc[o] = fmaf(hv, w2[h * H + o], acc[o]);
            }
            float dot = b3[rf];
#pragma unroll
            for (int o = 0; o < H; ++o) {
                float v = fmaxf(acc[o], 0.01f * acc[o]);  // lrelu, exact
                dot = fmaf(v, w3[o], dot);
            }
            float mm = 1.0f / (1.0f + expf(-dot));        // sigmoid
            m[f] = fmaxf(mm, SMALL_NUM_F);
        }

        const bool c = sh_cond[r] != 0.0f;
        float X[F];
        float ssum = 0.f;
#pragma unroll
        for (int f = 0; f < F; ++f) {
            float g = sh_g[r][f];
            float xw = expf(0.1f * (g / m[f]));
            if (c) xw *= g;
            X[f] = xw;
            ssum += xw;
        }
        float st = 0.f;
#pragma unroll
        for (int f = 0; f < F; ++f)
            st += m[f] * (X[f] / ssum) * sh_g[r][f];
        strength[r] = isnan(st) ? 0.0f : st;
    }

    const float r0 = strength[0], r1 = strength[1], r2 = strength[2];
    const float p0 = r0 * r1;
    const float p1 = r0 * (1.0f - r1);
    const float p2 = (1.0f - r0) * r2;
    const float p3 = (1.0f - r0) * (1.0f - r2);
    int idx = 0;
    float best = p0;
    if (p1 > best) { best = p1; idx = 1; }
    if (p2 > best) { best = p2; idx = 2; }
    if (p3 > best) { best = p3; idx = 3; }
    sh_idx[tid] = (unsigned char)idx;
    __syncthreads();

    // coalesced output: 256*18 floats per block
    float* outb = out + (size_t)blockIdx.x * (256 * A);
    for (int i = tid; i < 256 * A; i += 256) {
        int bl = i / A;
        int a  = i - bl * A;
        outb[i] = sh_leaves[sh_idx[bl]][a];
    }
}

extern "C" void kernel_launch(void* const* d_in, const int* in_sizes, int n_in,
                              void* d_out, int out_size, void* d_ws, size_t ws_size,
                              hipStream_t stream) {
    const float* s  = (const float*)d_in[0];
    const float* W1 = (const float*)d_in[1];
    const float* b1 = (const float*)d_in[2];
    const float* W2 = (const float*)d_in[3];
    const float* b2 = (const float*)d_in[4];
    const float* W3 = (const float*)d_in[5];
    const float* b3 = (const float*)d_in[6];
    const float* ps = (const float*)d_in[7];
    const float* lv = (const float*)d_in[8];
    const float* gn = (const float*)d_in[9];
    float* out = (float*)d_out;

    dim3 grid(BTOT / 256);
    dim3 block(256);
    hipLaunchKernelGGL(ftc_kernel, grid, block, 0, stream,
                       s, W1, b1, W2, b2, W3, b3, ps, lv, gn, out);
}